// Round 12
// baseline (253.433 us; speedup 1.0000x reference)
//
#include <hip/hip_runtime.h>
#include <hip/hip_fp16.h>

// GraphSAGE 2-layer encoder — R21.
// R20 postmortem: 234.0 (-3.2, single-read partition). Gathers (~130us) are
// measured-flat at the random-row request-path ceiling (~2.8 TB/s) across 4
// independent probes. Last untested lever: partition-branch PARALLELISM.
// R21: CHUNK 4096->2048 (391->782 partition blocks, 2x latency-hiding wave
// pool for the hist/flush/scatter chain; 8 edges/thread staging). Flush
// atomics rise ~1.6x but stay sharded across 8x1563 counters. All else
// identical to R20. Decision rule: flat => partition at atomic-throughput
// floor => every phase at a measured ceiling => ROOFLINE next round.

#define DIM 64
#define BN 64                 // nodes per bucket (dst >> 6)
#define CAP 2048              // P slots per bucket (8 shards x 256)
#define SEG 256               // slots per (bucket, shard); mean 128, +11 sigma
#define CHUNK 2048            // edges per partition block (= 8 * 256)
#define EPT 8                 // edges per thread in partition staging
#define WT_STRIDE 72          // padded k-stride of W^T / h1 tile in LDS (halves)

using f16x8 = __attribute__((ext_vector_type(8))) _Float16;
using f32x4 = __attribute__((ext_vector_type(4))) float;

// accumulate 8 halves (float4 bit-pattern) into acc[8]
__device__ inline void addh8(float* acc, float4 raw) {
    const __half2* hp = (const __half2*)&raw;
#pragma unroll
    for (int k = 0; k < 4; ++k) {
        float2 f = __half22float2(hp[k]);
        acc[2 * k]     += f.x;
        acc[2 * k + 1] += f.y;
    }
}

// gather c edges' A-rows (16B/lane slice at doff) with 8-deep MLP
__device__ inline void gather_rows(const __half* __restrict__ A, const int* sp, int c,
                                   size_t doff, float* acc) {
    int j = 0;
    for (; j + 8 <= c; j += 8) {
        float4 r0 = *(const float4*)&A[(size_t)sp[j + 0] * 64 + doff];
        float4 r1 = *(const float4*)&A[(size_t)sp[j + 1] * 64 + doff];
        float4 r2 = *(const float4*)&A[(size_t)sp[j + 2] * 64 + doff];
        float4 r3 = *(const float4*)&A[(size_t)sp[j + 3] * 64 + doff];
        float4 r4 = *(const float4*)&A[(size_t)sp[j + 4] * 64 + doff];
        float4 r5 = *(const float4*)&A[(size_t)sp[j + 5] * 64 + doff];
        float4 r6 = *(const float4*)&A[(size_t)sp[j + 6] * 64 + doff];
        float4 r7 = *(const float4*)&A[(size_t)sp[j + 7] * 64 + doff];
        addh8(acc, r0); addh8(acc, r1); addh8(acc, r2); addh8(acc, r3);
        addh8(acc, r4); addh8(acc, r5); addh8(acc, r6); addh8(acc, r7);
    }
    if (j + 4 <= c) {
        float4 r0 = *(const float4*)&A[(size_t)sp[j + 0] * 64 + doff];
        float4 r1 = *(const float4*)&A[(size_t)sp[j + 1] * 64 + doff];
        float4 r2 = *(const float4*)&A[(size_t)sp[j + 2] * 64 + doff];
        float4 r3 = *(const float4*)&A[(size_t)sp[j + 3] * 64 + doff];
        addh8(acc, r0); addh8(acc, r1); addh8(acc, r2); addh8(acc, r3);
        j += 4;
    }
    for (; j < c; ++j) {
        float4 rr = *(const float4*)&A[(size_t)sp[j] * 64 + doff];
        addh8(acc, rr);
    }
}

// ---- B-fragment loader (fp32 rows): lane's node row, k = ki*32 + quad*8 + j ----
__device__ inline void load_bfrag(const float* __restrict__ H, long long nn, int lq,
                                  f16x8& b0, f16x8& b1) {
    const float* p = &H[nn * 64 + lq * 8];
    float4 u0 = *(const float4*)p;
    float4 u1 = *(const float4*)(p + 4);
    float4 u2 = *(const float4*)(p + 32);
    float4 u3 = *(const float4*)(p + 36);
    b0[0] = (_Float16)u0.x; b0[1] = (_Float16)u0.y; b0[2] = (_Float16)u0.z; b0[3] = (_Float16)u0.w;
    b0[4] = (_Float16)u1.x; b0[5] = (_Float16)u1.y; b0[6] = (_Float16)u1.z; b0[7] = (_Float16)u1.w;
    b1[0] = (_Float16)u2.x; b1[1] = (_Float16)u2.y; b1[2] = (_Float16)u2.z; b1[3] = (_Float16)u2.w;
    b1[4] = (_Float16)u3.x; b1[5] = (_Float16)u3.y; b1[6] = (_Float16)u3.z; b1[7] = (_Float16)u3.w;
}

// ---- MFMA dual-GEMM body (layer 1, fp32 input): A=H@Wl ; D=H@Wr+bias ----
__device__ void gemm_body(int bid, __half* wt,
                          const float* __restrict__ H,
                          const float* __restrict__ Wl, const float* __restrict__ Wr,
                          const float* __restrict__ bias,
                          __half* __restrict__ A, __half* __restrict__ Dbuf, int n) {
    const int t = threadIdx.x;
    // stage W^T (fp16): wt[(mat*64 + m)*WT_STRIDE + k] = W[k][m]
    for (int i = t; i < 4096; i += 256) {
        int k = i >> 6, m = i & 63;
        wt[(size_t)m * WT_STRIDE + k] = __float2half(Wl[i]);
        wt[(size_t)(64 + m) * WT_STRIDE + k] = __float2half(Wr[i]);
    }
    __syncthreads();
    const int lane = t & 63, wave = t >> 6;
    const int ln = lane & 15, lq = lane >> 4;
    f16x8 af[2][4][2];
#pragma unroll
    for (int mat = 0; mat < 2; ++mat)
#pragma unroll
        for (int mt = 0; mt < 4; ++mt)
#pragma unroll
            for (int ki = 0; ki < 2; ++ki)
                af[mat][mt][ki] = *(const f16x8*)&wt[(size_t)(mat * 64 + mt * 16 + ln) * WT_STRIDE
                                                     + ki * 32 + lq * 8];
    float4 bf[4];
#pragma unroll
    for (int mt = 0; mt < 4; ++mt)
        bf[mt] = *(const float4*)&bias[mt * 16 + lq * 4];

    const int base = bid * 256;
    for (int it = 0; it < 4; ++it) {
        const int node = base + it * 64 + wave * 16 + ln;
        const long long nn = (node < n) ? node : (n - 1);
        f16x8 b0, b1;
        load_bfrag(H, nn, lq, b0, b1);
        f32x4 acc[2][4];
#pragma unroll
        for (int mat = 0; mat < 2; ++mat)
#pragma unroll
            for (int mt = 0; mt < 4; ++mt) {
                f32x4 z = {0.f, 0.f, 0.f, 0.f};
                z = __builtin_amdgcn_mfma_f32_16x16x32_f16(af[mat][mt][0], b0, z, 0, 0, 0);
                z = __builtin_amdgcn_mfma_f32_16x16x32_f16(af[mat][mt][1], b1, z, 0, 0, 0);
                acc[mat][mt] = z;
            }
        if (node < n) {
#pragma unroll
            for (int mt = 0; mt < 4; ++mt) {
                union { __half2 h[2]; float2 f; } u;
                u.h[0] = __floats2half2_rn(acc[0][mt][0], acc[0][mt][1]);
                u.h[1] = __floats2half2_rn(acc[0][mt][2], acc[0][mt][3]);
                *(float2*)&A[(size_t)node * 64 + mt * 16 + lq * 4] = u.f;
                union { __half2 h[2]; float2 f; } v;
                v.h[0] = __floats2half2_rn(acc[1][mt][0] + bf[mt].x, acc[1][mt][1] + bf[mt].y);
                v.h[1] = __floats2half2_rn(acc[1][mt][2] + bf[mt].z, acc[1][mt][3] + bf[mt].w);
                *(float2*)&Dbuf[(size_t)node * 64 + mt * 16 + lq * 4] = v.f;
            }
        }
    }
}

// ---- fused dispatch: blocks [0,pb) partition edges (single-read, sharded) ----
__global__ __launch_bounds__(256) void part_gemm_kernel(const int* __restrict__ src,
                                                        const int* __restrict__ dst,
                                                        int* __restrict__ gcur,
                                                        unsigned* __restrict__ P,
                                                        int nE, int nbuck, int pb,
                                                        const float* __restrict__ H,
                                                        const float* __restrict__ Wl,
                                                        const float* __restrict__ Wr,
                                                        const float* __restrict__ bias,
                                                        __half* __restrict__ A,
                                                        __half* __restrict__ Dbuf, int n) {
    __shared__ __align__(16) unsigned short smem_u[2 * 64 * WT_STRIDE];  // 18KB; >= 6.3KB hist
    if ((int)blockIdx.x < pb) {
        int* hist = (int*)smem_u;
        const int t = threadIdx.x;
        const int shard = (int)blockIdx.x & 7;
        int* gc = gcur + (size_t)shard * nbuck;
        for (int k = t; k < nbuck; k += 256) hist[k] = 0;
        __syncthreads();
        const int base = blockIdx.x * CHUNK;
        const int end = min(nE, base + CHUNK);
        // single global pass: stage (src,dst) into registers, hist from regs
        int dreg[EPT], sreg[EPT];
#pragma unroll
        for (int j = 0; j < EPT; ++j) {
            int i = base + t + j * 256;
            dreg[j] = -1;
            if (i < end) {
                dreg[j] = dst[i];
                sreg[j] = src[i];
                atomicAdd(&hist[dreg[j] >> 6], 1);
            }
        }
        __syncthreads();
        // reserve shard-local ranges (sharded counters, 8x fewer per line)
        for (int k = t; k < nbuck; k += 256) {
            int h = hist[k];
            hist[k] = h ? atomicAdd(&gc[k], h) : 0;
        }
        __syncthreads();
        // scatter from registers
#pragma unroll
        for (int j = 0; j < EPT; ++j) {
            int d = dreg[j];
            if (d >= 0) {
                int bk = d >> 6;
                int pos = atomicAdd(&hist[bk], 1);
                pos = min(pos, SEG - 1);   // hard safety (mean 128, +11 sigma)
                P[(size_t)bk * CAP + (shard << 8) + pos] =
                    ((unsigned)sreg[j] << 6) | (unsigned)(d & 63);
            }
        }
    } else {
        gemm_body(blockIdx.x - pb, (__half*)smem_u, H, Wl, Wr, bias, A, Dbuf, n);
    }
}

// ---- fused: layer-1 gather/combine/relu -> LDS h1 tile -> layer-2 dual GEMM.
// Bucket read ONCE into registers via 8-segment prefix map; hist from regs;
// node-sorted srcs scattered to LDS lsrc AND back into P in place (dense, so
// gather2 is untouched). Emits nstart/ncnt. Dynamic row scheduling.
// Din/D2 may alias. A2 must NOT alias A.
__global__ __launch_bounds__(256) void gather_gemm_kernel(const __half* __restrict__ A,
                                                          const __half* Din,
                                                          const int* __restrict__ gcur,
                                                          unsigned* __restrict__ P,
                                                          int* __restrict__ nstart,
                                                          int* __restrict__ ncnt,
                                                          const float* __restrict__ Wl,
                                                          const float* __restrict__ Wr,
                                                          const float* __restrict__ bias,
                                                          __half* __restrict__ A2,
                                                          __half* D2, int n) {
    __shared__ int hist[BN];
    __shared__ int rstart[BN];
    __shared__ int cur[BN];
    __shared__ int wq;
    __shared__ int segoff[9];
    __shared__ __align__(16) unsigned char uni[2 * 64 * WT_STRIDE * 2];  // 18KB: lsrc | wt
    __shared__ __align__(16) __half tile[64 * WT_STRIDE];                // 9KB h1 tile
    int* lsrc = (int*)uni;
    __half* wt = (__half*)uni;
    const int t = threadIdx.x;
    const int b = blockIdx.x;
    const int nbuck = gridDim.x;
    // pre-load W into registers (fire-and-forget; consumed post-gather)
    float4 wl4[4], wr4[4];
#pragma unroll
    for (int j = 0; j < 4; ++j) {
        wl4[j] = ((const float4*)Wl)[j * 256 + t];
        wr4[j] = ((const float4*)Wr)[j * 256 + t];
    }
    if (t < BN) hist[t] = 0;
    if (t == 0) {
        wq = 32;
        int acc = 0;
        segoff[0] = 0;
#pragma unroll
        for (int s = 0; s < 8; ++s) {
            int c = gcur[(size_t)s * nbuck + b];
            acc += min(c, SEG);
            segoff[s + 1] = acc;
        }
    }
    __syncthreads();
    const unsigned pbase = (unsigned)b * CAP;
    const int cnt = segoff[8];
    // read bucket edges ONCE into registers (8-segment map); hist from regs
    unsigned ereg[8];
#pragma unroll
    for (int j = 0; j < 8; ++j) {
        int i = t + j * 256;
        ereg[j] = 0u;
        if (i < cnt) {
            int s = 0;
#pragma unroll
            for (int q = 1; q < 8; ++q) s += (i >= segoff[q]);
            unsigned p = P[pbase + (unsigned)(s << 8) + (unsigned)(i - segoff[s])];
            ereg[j] = p;
            atomicAdd(&hist[p & 63], 1);
        }
    }
    __syncthreads();
    if (t < 64) {   // wave 0: exclusive scan of 64 counts via shuffles
        int v = hist[t];
        int s = v;
#pragma unroll
        for (int d = 1; d < 64; d <<= 1) {
            int u = __shfl_up(s, d);
            if (t >= d) s += u;
        }
        rstart[t] = s - v;
        cur[t] = s - v;
    }
    __syncthreads();
    // emit per-node CSR (absolute start in P + count)
    if (t < 64) {
        int node = b * BN + t;
        if (node < n) { nstart[node] = (int)pbase + rstart[t]; ncnt[node] = hist[t]; }
    }
    // scatter node-sorted srcs: LDS (read path) + P in place, DENSE from pbase
    // (gather2's list). The barrier above drained all reads of P's segments.
#pragma unroll
    for (int j = 0; j < 8; ++j) {
        int i = t + j * 256;
        if (i < cnt) {
            unsigned p = ereg[j];
            int pos = atomicAdd(&cur[p & 63], 1);
            int v = (int)(p >> 6);
            lsrc[pos] = v;
            ((int*)P)[pbase + pos] = v;
        }
    }
    __syncthreads();
    // ---- node loop: dynamic row scheduling (8-lane groups grab rows) ----
    const int dg = t & 7;
    const size_t doff = (size_t)dg * 8;
    int r = t >> 3;                 // groups 0..31 start at rows 0..31
    while (r < BN) {
        const int node = b * BN + r;
        float o[8] = {0.f, 0.f, 0.f, 0.f, 0.f, 0.f, 0.f, 0.f};
        if (node < n) {
            const int c = hist[r];
            float acc[8] = {0.f, 0.f, 0.f, 0.f, 0.f, 0.f, 0.f, 0.f};
            gather_rows(A, lsrc + rstart[r], c, doff, acc);
            const float inv = 1.0f / fmaxf((float)c, 1.0f);
            float d8[8] = {0.f, 0.f, 0.f, 0.f, 0.f, 0.f, 0.f, 0.f};
            addh8(d8, *(const float4*)&Din[(size_t)node * 64 + doff]);
#pragma unroll
            for (int k = 0; k < 8; ++k)
                o[k] = fmaxf(fmaf(acc[k], inv, d8[k]), 0.f);   // relu (layer 1)
        }
        // write h1 fragment to LDS tile (zeros for padded rows)
        union { __half2 h[4]; float4 f; } u;
#pragma unroll
        for (int k = 0; k < 4; ++k)
            u.h[k] = __floats2half2_rn(o[2 * k], o[2 * k + 1]);
        *(float4*)&tile[(size_t)r * WT_STRIDE + doff] = u.f;
        // grab next row
        int nr;
        if (dg == 0) nr = atomicAdd(&wq, 1);
        nr = __shfl(nr, (t & 63) & ~7, 64);
        r = nr;
    }
    __syncthreads();               // lsrc dead from here; region becomes wt
    // stage W^T (fp16) from the pre-loaded registers
#pragma unroll
    for (int j = 0; j < 4; ++j) {
#pragma unroll
        for (int e = 0; e < 4; ++e) {
            int i = 4 * (j * 256 + t) + e;
            int k = i >> 6, m = i & 63;
            wt[(size_t)m * WT_STRIDE + k] = __float2half(((const float*)&wl4[j])[e]);
            wt[(size_t)(64 + m) * WT_STRIDE + k] = __float2half(((const float*)&wr4[j])[e]);
        }
    }
    __syncthreads();
    // ---- layer-2 dual GEMM on the 64x64 LDS tile ----
    const int lane = t & 63, wave = t >> 6;
    const int ln = lane & 15, lq = lane >> 4;
    f16x8 af[2][4][2];
#pragma unroll
    for (int mat = 0; mat < 2; ++mat)
#pragma unroll
        for (int mt = 0; mt < 4; ++mt)
#pragma unroll
            for (int ki = 0; ki < 2; ++ki)
                af[mat][mt][ki] = *(const f16x8*)&wt[(size_t)(mat * 64 + mt * 16 + ln) * WT_STRIDE
                                                     + ki * 32 + lq * 8];
    float4 bf[4];
#pragma unroll
    for (int mt = 0; mt < 4; ++mt)
        bf[mt] = *(const float4*)&bias[mt * 16 + lq * 4];

    const int r2 = wave * 16 + ln;
    f16x8 b0 = *(const f16x8*)&tile[(size_t)r2 * WT_STRIDE + lq * 8];
    f16x8 b1 = *(const f16x8*)&tile[(size_t)r2 * WT_STRIDE + 32 + lq * 8];
    f32x4 acc2[2][4];
#pragma unroll
    for (int mat = 0; mat < 2; ++mat)
#pragma unroll
        for (int mt = 0; mt < 4; ++mt) {
            f32x4 z = {0.f, 0.f, 0.f, 0.f};
            z = __builtin_amdgcn_mfma_f32_16x16x32_f16(af[mat][mt][0], b0, z, 0, 0, 0);
            z = __builtin_amdgcn_mfma_f32_16x16x32_f16(af[mat][mt][1], b1, z, 0, 0, 0);
            acc2[mat][mt] = z;
        }
    const int node = b * BN + r2;
    if (node < n) {
#pragma unroll
        for (int mt = 0; mt < 4; ++mt) {
            union { __half2 h[2]; float2 f; } u;
            u.h[0] = __floats2half2_rn(acc2[0][mt][0], acc2[0][mt][1]);
            u.h[1] = __floats2half2_rn(acc2[0][mt][2], acc2[0][mt][3]);
            *(float2*)&A2[(size_t)node * 64 + mt * 16 + lq * 4] = u.f;
            union { __half2 h[2]; float2 f; } v;
            v.h[0] = __floats2half2_rn(acc2[1][mt][0] + bf[mt].x, acc2[1][mt][1] + bf[mt].y);
            v.h[1] = __floats2half2_rn(acc2[1][mt][2] + bf[mt].z, acc2[1][mt][3] + bf[mt].w);
            *(float2*)&D2[(size_t)node * 64 + mt * 16 + lq * 4] = v.f;
        }
    }
}

// ---- layer-2 gather from node-sorted P (nstart/ncnt), dynamic rows ----
__global__ __launch_bounds__(256) void gather_csr_combine(const __half* __restrict__ A,
                                                          const __half* __restrict__ Dbuf,
                                                          const int* __restrict__ nstart,
                                                          const int* __restrict__ ncnt,
                                                          const int* __restrict__ P2,
                                                          float* __restrict__ out, int n) {
    __shared__ int wq;
    const int t = threadIdx.x;
    const int b = blockIdx.x;
    if (t == 0) wq = 32;
    __syncthreads();
    const int dg = t & 7;
    const size_t doff = (size_t)dg * 8;
    int r = t >> 3;
    while (r < BN) {
        const int node = b * BN + r;
        if (node < n) {
            const int s0 = nstart[node];
            const int c = ncnt[node];
            float acc[8] = {0.f, 0.f, 0.f, 0.f, 0.f, 0.f, 0.f, 0.f};
            gather_rows(A, P2 + s0, c, doff, acc);
            const float inv = 1.0f / fmaxf((float)c, 1.0f);
            float d8[8] = {0.f, 0.f, 0.f, 0.f, 0.f, 0.f, 0.f, 0.f};
            addh8(d8, *(const float4*)&Dbuf[(size_t)node * 64 + doff]);
            float o[8];
#pragma unroll
            for (int k = 0; k < 8; ++k)
                o[k] = fmaf(acc[k], inv, d8[k]);
            f32x4 v0 = {o[0], o[1], o[2], o[3]};
            f32x4 v1 = {o[4], o[5], o[6], o[7]};
            __builtin_nontemporal_store(v0, (f32x4*)&out[(size_t)node * 64 + doff]);
            __builtin_nontemporal_store(v1, (f32x4*)&out[(size_t)node * 64 + doff + 4]);
        }
        int nr;
        if (dg == 0) nr = atomicAdd(&wq, 1);
        nr = __shfl(nr, (t & 63) & ~7, 64);
        r = nr;
    }
}

extern "C" void kernel_launch(void* const* d_in, const int* in_sizes, int n_in,
                              void* d_out, int out_size, void* d_ws, size_t ws_size,
                              hipStream_t stream) {
    const float* x   = (const float*)d_in[0];
    const int*   ei  = (const int*)d_in[1];
    const float* w1l = (const float*)d_in[2];
    const float* b1l = (const float*)d_in[3];
    const float* w1r = (const float*)d_in[4];
    const float* w2l = (const float*)d_in[5];
    const float* b2l = (const float*)d_in[6];
    const float* w2r = (const float*)d_in[7];
    float* out = (float*)d_out;

    const int N = in_sizes[0] / DIM;   // 100000
    const int E = in_sizes[1] / 2;     // 1600000
    const int* src = ei;
    const int* dst = ei + E;
    const int nbuck = (N + BN - 1) / BN;           // 1563
    const int pb = (E + CHUNK - 1) / CHUNK;        // 782
    const int gb = (N + 255) / 256;                // 391

    // ws: gcur[8*nbuck] | nstart[N] | ncnt[N] | P[nbuck*CAP] |
    //     (align 16) A fp16[N*64] | D fp16[N*64] (=D2) | A2 fp16[N*64]
    int* gcur = (int*)d_ws;
    int* nstart = gcur + 8 * nbuck;
    int* ncnt = nstart + N;
    unsigned* P = (unsigned*)(ncnt + N);
    uintptr_t ap = (uintptr_t)(P + (size_t)nbuck * CAP);
    ap = (ap + 15) & ~(uintptr_t)15;
    __half* A  = (__half*)ap;
    __half* D  = A + (size_t)N * DIM;
    __half* A2 = D + (size_t)N * DIM;

    // ---- build (sharded capacity buckets, single-read) + layer-1 gemm ----
    hipMemsetAsync(gcur, 0, 8 * nbuck * sizeof(int), stream);
    part_gemm_kernel<<<pb + gb, 256, 0, stream>>>(src, dst, gcur, P, E, nbuck, pb,
                                                  x, w1l, w1r, b1l, A, D, N);

    // ---- layer-1 gather + relu + layer-2 gemm (fused); compacts P in place ----
    gather_gemm_kernel<<<nbuck, 256, 0, stream>>>(A, D, gcur, P, nstart, ncnt,
                                                  w2l, w2r, b2l, A2, D, N);

    // ---- layer-2 gather -> fp32 out ----
    gather_csr_combine<<<nbuck, 256, 0, stream>>>(A2, D, nstart, ncnt, (const int*)P, out, N);
}

// Round 13
// 231.948 us; speedup vs baseline: 1.0926x; 1.0926x over previous
//
#include <hip/hip_runtime.h>
#include <hip/hip_fp16.h>

// GraphSAGE 2-layer encoder — R22 (= R20 revert; best measured 234.0us).
// R21 postmortem: CHUNK 4096->2048 REGRESSED (+19us): per-block fixed cost
// (zero+flush 1563 counters) is CHUNK-independent, so 2x blocks = 2x total
// flush work; partition was not parallelism-starved. Pre-committed decision
// rule fired: part_gemm at its structural floor at CHUNK=4096.
// Roofline case: gathers flat at ~2.8TB/s random-row request-path ceiling
// across 4 independent probes (R14 occupancy / R15 balance / R18 MLP / R19);
// partition atomic levers exhausted (R19 -11, R20 -3, R21 regressed).
// This kernel = R20 exactly: sharded capacity-bucketed single-read partition,
// fused L1 dual-GEMM, fused gather1+L2-GEMM with in-place P compaction,
// sort-free CSR gather2 with nontemporal stores.

#define DIM 64
#define BN 64                 // nodes per bucket (dst >> 6)
#define CAP 2048              // P slots per bucket (8 shards x 256)
#define SEG 256               // slots per (bucket, shard); mean 128, +11 sigma
#define CHUNK 4096            // edges per partition block (= 16 * 256)
#define WT_STRIDE 72          // padded k-stride of W^T / h1 tile in LDS (halves)

using f16x8 = __attribute__((ext_vector_type(8))) _Float16;
using f32x4 = __attribute__((ext_vector_type(4))) float;

// accumulate 8 halves (float4 bit-pattern) into acc[8]
__device__ inline void addh8(float* acc, float4 raw) {
    const __half2* hp = (const __half2*)&raw;
#pragma unroll
    for (int k = 0; k < 4; ++k) {
        float2 f = __half22float2(hp[k]);
        acc[2 * k]     += f.x;
        acc[2 * k + 1] += f.y;
    }
}

// gather c edges' A-rows (16B/lane slice at doff) with 8-deep MLP
__device__ inline void gather_rows(const __half* __restrict__ A, const int* sp, int c,
                                   size_t doff, float* acc) {
    int j = 0;
    for (; j + 8 <= c; j += 8) {
        float4 r0 = *(const float4*)&A[(size_t)sp[j + 0] * 64 + doff];
        float4 r1 = *(const float4*)&A[(size_t)sp[j + 1] * 64 + doff];
        float4 r2 = *(const float4*)&A[(size_t)sp[j + 2] * 64 + doff];
        float4 r3 = *(const float4*)&A[(size_t)sp[j + 3] * 64 + doff];
        float4 r4 = *(const float4*)&A[(size_t)sp[j + 4] * 64 + doff];
        float4 r5 = *(const float4*)&A[(size_t)sp[j + 5] * 64 + doff];
        float4 r6 = *(const float4*)&A[(size_t)sp[j + 6] * 64 + doff];
        float4 r7 = *(const float4*)&A[(size_t)sp[j + 7] * 64 + doff];
        addh8(acc, r0); addh8(acc, r1); addh8(acc, r2); addh8(acc, r3);
        addh8(acc, r4); addh8(acc, r5); addh8(acc, r6); addh8(acc, r7);
    }
    if (j + 4 <= c) {
        float4 r0 = *(const float4*)&A[(size_t)sp[j + 0] * 64 + doff];
        float4 r1 = *(const float4*)&A[(size_t)sp[j + 1] * 64 + doff];
        float4 r2 = *(const float4*)&A[(size_t)sp[j + 2] * 64 + doff];
        float4 r3 = *(const float4*)&A[(size_t)sp[j + 3] * 64 + doff];
        addh8(acc, r0); addh8(acc, r1); addh8(acc, r2); addh8(acc, r3);
        j += 4;
    }
    for (; j < c; ++j) {
        float4 rr = *(const float4*)&A[(size_t)sp[j] * 64 + doff];
        addh8(acc, rr);
    }
}

// ---- B-fragment loader (fp32 rows): lane's node row, k = ki*32 + quad*8 + j ----
__device__ inline void load_bfrag(const float* __restrict__ H, long long nn, int lq,
                                  f16x8& b0, f16x8& b1) {
    const float* p = &H[nn * 64 + lq * 8];
    float4 u0 = *(const float4*)p;
    float4 u1 = *(const float4*)(p + 4);
    float4 u2 = *(const float4*)(p + 32);
    float4 u3 = *(const float4*)(p + 36);
    b0[0] = (_Float16)u0.x; b0[1] = (_Float16)u0.y; b0[2] = (_Float16)u0.z; b0[3] = (_Float16)u0.w;
    b0[4] = (_Float16)u1.x; b0[5] = (_Float16)u1.y; b0[6] = (_Float16)u1.z; b0[7] = (_Float16)u1.w;
    b1[0] = (_Float16)u2.x; b1[1] = (_Float16)u2.y; b1[2] = (_Float16)u2.z; b1[3] = (_Float16)u2.w;
    b1[4] = (_Float16)u3.x; b1[5] = (_Float16)u3.y; b1[6] = (_Float16)u3.z; b1[7] = (_Float16)u3.w;
}

// ---- MFMA dual-GEMM body (layer 1, fp32 input): A=H@Wl ; D=H@Wr+bias ----
__device__ void gemm_body(int bid, __half* wt,
                          const float* __restrict__ H,
                          const float* __restrict__ Wl, const float* __restrict__ Wr,
                          const float* __restrict__ bias,
                          __half* __restrict__ A, __half* __restrict__ Dbuf, int n) {
    const int t = threadIdx.x;
    // stage W^T (fp16): wt[(mat*64 + m)*WT_STRIDE + k] = W[k][m]
    for (int i = t; i < 4096; i += 256) {
        int k = i >> 6, m = i & 63;
        wt[(size_t)m * WT_STRIDE + k] = __float2half(Wl[i]);
        wt[(size_t)(64 + m) * WT_STRIDE + k] = __float2half(Wr[i]);
    }
    __syncthreads();
    const int lane = t & 63, wave = t >> 6;
    const int ln = lane & 15, lq = lane >> 4;
    f16x8 af[2][4][2];
#pragma unroll
    for (int mat = 0; mat < 2; ++mat)
#pragma unroll
        for (int mt = 0; mt < 4; ++mt)
#pragma unroll
            for (int ki = 0; ki < 2; ++ki)
                af[mat][mt][ki] = *(const f16x8*)&wt[(size_t)(mat * 64 + mt * 16 + ln) * WT_STRIDE
                                                     + ki * 32 + lq * 8];
    float4 bf[4];
#pragma unroll
    for (int mt = 0; mt < 4; ++mt)
        bf[mt] = *(const float4*)&bias[mt * 16 + lq * 4];

    const int base = bid * 256;
    for (int it = 0; it < 4; ++it) {
        const int node = base + it * 64 + wave * 16 + ln;
        const long long nn = (node < n) ? node : (n - 1);
        f16x8 b0, b1;
        load_bfrag(H, nn, lq, b0, b1);
        f32x4 acc[2][4];
#pragma unroll
        for (int mat = 0; mat < 2; ++mat)
#pragma unroll
            for (int mt = 0; mt < 4; ++mt) {
                f32x4 z = {0.f, 0.f, 0.f, 0.f};
                z = __builtin_amdgcn_mfma_f32_16x16x32_f16(af[mat][mt][0], b0, z, 0, 0, 0);
                z = __builtin_amdgcn_mfma_f32_16x16x32_f16(af[mat][mt][1], b1, z, 0, 0, 0);
                acc[mat][mt] = z;
            }
        if (node < n) {
#pragma unroll
            for (int mt = 0; mt < 4; ++mt) {
                union { __half2 h[2]; float2 f; } u;
                u.h[0] = __floats2half2_rn(acc[0][mt][0], acc[0][mt][1]);
                u.h[1] = __floats2half2_rn(acc[0][mt][2], acc[0][mt][3]);
                *(float2*)&A[(size_t)node * 64 + mt * 16 + lq * 4] = u.f;
                union { __half2 h[2]; float2 f; } v;
                v.h[0] = __floats2half2_rn(acc[1][mt][0] + bf[mt].x, acc[1][mt][1] + bf[mt].y);
                v.h[1] = __floats2half2_rn(acc[1][mt][2] + bf[mt].z, acc[1][mt][3] + bf[mt].w);
                *(float2*)&Dbuf[(size_t)node * 64 + mt * 16 + lq * 4] = v.f;
            }
        }
    }
}

// ---- fused dispatch: blocks [0,pb) partition edges (single-read, sharded) ----
__global__ __launch_bounds__(256) void part_gemm_kernel(const int* __restrict__ src,
                                                        const int* __restrict__ dst,
                                                        int* __restrict__ gcur,
                                                        unsigned* __restrict__ P,
                                                        int nE, int nbuck, int pb,
                                                        const float* __restrict__ H,
                                                        const float* __restrict__ Wl,
                                                        const float* __restrict__ Wr,
                                                        const float* __restrict__ bias,
                                                        __half* __restrict__ A,
                                                        __half* __restrict__ Dbuf, int n) {
    __shared__ __align__(16) unsigned short smem_u[2 * 64 * WT_STRIDE];  // 18KB; >= 6.3KB hist
    if ((int)blockIdx.x < pb) {
        int* hist = (int*)smem_u;
        const int t = threadIdx.x;
        const int shard = (int)blockIdx.x & 7;
        int* gc = gcur + (size_t)shard * nbuck;
        for (int k = t; k < nbuck; k += 256) hist[k] = 0;
        __syncthreads();
        const int base = blockIdx.x * CHUNK;
        const int end = min(nE, base + CHUNK);
        // single global pass: stage (src,dst) into registers, hist from regs
        int dreg[16], sreg[16];
#pragma unroll
        for (int j = 0; j < 16; ++j) {
            int i = base + t + j * 256;
            dreg[j] = -1;
            if (i < end) {
                dreg[j] = dst[i];
                sreg[j] = src[i];
                atomicAdd(&hist[dreg[j] >> 6], 1);
            }
        }
        __syncthreads();
        // reserve shard-local ranges (sharded counters, 8x fewer per line)
        for (int k = t; k < nbuck; k += 256) {
            int h = hist[k];
            hist[k] = h ? atomicAdd(&gc[k], h) : 0;
        }
        __syncthreads();
        // scatter from registers
#pragma unroll
        for (int j = 0; j < 16; ++j) {
            int d = dreg[j];
            if (d >= 0) {
                int bk = d >> 6;
                int pos = atomicAdd(&hist[bk], 1);
                pos = min(pos, SEG - 1);   // hard safety (mean 128, +11 sigma)
                P[(size_t)bk * CAP + (shard << 8) + pos] =
                    ((unsigned)sreg[j] << 6) | (unsigned)(d & 63);
            }
        }
    } else {
        gemm_body(blockIdx.x - pb, (__half*)smem_u, H, Wl, Wr, bias, A, Dbuf, n);
    }
}

// ---- fused: layer-1 gather/combine/relu -> LDS h1 tile -> layer-2 dual GEMM.
// Bucket read ONCE into registers via 8-segment prefix map; hist from regs;
// node-sorted srcs scattered to LDS lsrc AND back into P in place (dense, so
// gather2 is untouched). Emits nstart/ncnt. Dynamic row scheduling.
// Din/D2 may alias. A2 must NOT alias A.
__global__ __launch_bounds__(256) void gather_gemm_kernel(const __half* __restrict__ A,
                                                          const __half* Din,
                                                          const int* __restrict__ gcur,
                                                          unsigned* __restrict__ P,
                                                          int* __restrict__ nstart,
                                                          int* __restrict__ ncnt,
                                                          const float* __restrict__ Wl,
                                                          const float* __restrict__ Wr,
                                                          const float* __restrict__ bias,
                                                          __half* __restrict__ A2,
                                                          __half* D2, int n) {
    __shared__ int hist[BN];
    __shared__ int rstart[BN];
    __shared__ int cur[BN];
    __shared__ int wq;
    __shared__ int segoff[9];
    __shared__ __align__(16) unsigned char uni[2 * 64 * WT_STRIDE * 2];  // 18KB: lsrc | wt
    __shared__ __align__(16) __half tile[64 * WT_STRIDE];                // 9KB h1 tile
    int* lsrc = (int*)uni;
    __half* wt = (__half*)uni;
    const int t = threadIdx.x;
    const int b = blockIdx.x;
    const int nbuck = gridDim.x;
    // pre-load W into registers (fire-and-forget; consumed post-gather)
    float4 wl4[4], wr4[4];
#pragma unroll
    for (int j = 0; j < 4; ++j) {
        wl4[j] = ((const float4*)Wl)[j * 256 + t];
        wr4[j] = ((const float4*)Wr)[j * 256 + t];
    }
    if (t < BN) hist[t] = 0;
    if (t == 0) {
        wq = 32;
        int acc = 0;
        segoff[0] = 0;
#pragma unroll
        for (int s = 0; s < 8; ++s) {
            int c = gcur[(size_t)s * nbuck + b];
            acc += min(c, SEG);
            segoff[s + 1] = acc;
        }
    }
    __syncthreads();
    const unsigned pbase = (unsigned)b * CAP;
    const int cnt = segoff[8];
    // read bucket edges ONCE into registers (8-segment map); hist from regs
    unsigned ereg[8];
#pragma unroll
    for (int j = 0; j < 8; ++j) {
        int i = t + j * 256;
        ereg[j] = 0u;
        if (i < cnt) {
            int s = 0;
#pragma unroll
            for (int q = 1; q < 8; ++q) s += (i >= segoff[q]);
            unsigned p = P[pbase + (unsigned)(s << 8) + (unsigned)(i - segoff[s])];
            ereg[j] = p;
            atomicAdd(&hist[p & 63], 1);
        }
    }
    __syncthreads();
    if (t < 64) {   // wave 0: exclusive scan of 64 counts via shuffles
        int v = hist[t];
        int s = v;
#pragma unroll
        for (int d = 1; d < 64; d <<= 1) {
            int u = __shfl_up(s, d);
            if (t >= d) s += u;
        }
        rstart[t] = s - v;
        cur[t] = s - v;
    }
    __syncthreads();
    // emit per-node CSR (absolute start in P + count)
    if (t < 64) {
        int node = b * BN + t;
        if (node < n) { nstart[node] = (int)pbase + rstart[t]; ncnt[node] = hist[t]; }
    }
    // scatter node-sorted srcs: LDS (read path) + P in place, DENSE from pbase
    // (gather2's list). The barrier above drained all reads of P's segments.
#pragma unroll
    for (int j = 0; j < 8; ++j) {
        int i = t + j * 256;
        if (i < cnt) {
            unsigned p = ereg[j];
            int pos = atomicAdd(&cur[p & 63], 1);
            int v = (int)(p >> 6);
            lsrc[pos] = v;
            ((int*)P)[pbase + pos] = v;
        }
    }
    __syncthreads();
    // ---- node loop: dynamic row scheduling (8-lane groups grab rows) ----
    const int dg = t & 7;
    const size_t doff = (size_t)dg * 8;
    int r = t >> 3;                 // groups 0..31 start at rows 0..31
    while (r < BN) {
        const int node = b * BN + r;
        float o[8] = {0.f, 0.f, 0.f, 0.f, 0.f, 0.f, 0.f, 0.f};
        if (node < n) {
            const int c = hist[r];
            float acc[8] = {0.f, 0.f, 0.f, 0.f, 0.f, 0.f, 0.f, 0.f};
            gather_rows(A, lsrc + rstart[r], c, doff, acc);
            const float inv = 1.0f / fmaxf((float)c, 1.0f);
            float d8[8] = {0.f, 0.f, 0.f, 0.f, 0.f, 0.f, 0.f, 0.f};
            addh8(d8, *(const float4*)&Din[(size_t)node * 64 + doff]);
#pragma unroll
            for (int k = 0; k < 8; ++k)
                o[k] = fmaxf(fmaf(acc[k], inv, d8[k]), 0.f);   // relu (layer 1)
        }
        // write h1 fragment to LDS tile (zeros for padded rows)
        union { __half2 h[4]; float4 f; } u;
#pragma unroll
        for (int k = 0; k < 4; ++k)
            u.h[k] = __floats2half2_rn(o[2 * k], o[2 * k + 1]);
        *(float4*)&tile[(size_t)r * WT_STRIDE + doff] = u.f;
        // grab next row
        int nr;
        if (dg == 0) nr = atomicAdd(&wq, 1);
        nr = __shfl(nr, (t & 63) & ~7, 64);
        r = nr;
    }
    __syncthreads();               // lsrc dead from here; region becomes wt
    // stage W^T (fp16) from the pre-loaded registers
#pragma unroll
    for (int j = 0; j < 4; ++j) {
#pragma unroll
        for (int e = 0; e < 4; ++e) {
            int i = 4 * (j * 256 + t) + e;
            int k = i >> 6, m = i & 63;
            wt[(size_t)m * WT_STRIDE + k] = __float2half(((const float*)&wl4[j])[e]);
            wt[(size_t)(64 + m) * WT_STRIDE + k] = __float2half(((const float*)&wr4[j])[e]);
        }
    }
    __syncthreads();
    // ---- layer-2 dual GEMM on the 64x64 LDS tile ----
    const int lane = t & 63, wave = t >> 6;
    const int ln = lane & 15, lq = lane >> 4;
    f16x8 af[2][4][2];
#pragma unroll
    for (int mat = 0; mat < 2; ++mat)
#pragma unroll
        for (int mt = 0; mt < 4; ++mt)
#pragma unroll
            for (int ki = 0; ki < 2; ++ki)
                af[mat][mt][ki] = *(const f16x8*)&wt[(size_t)(mat * 64 + mt * 16 + ln) * WT_STRIDE
                                                     + ki * 32 + lq * 8];
    float4 bf[4];
#pragma unroll
    for (int mt = 0; mt < 4; ++mt)
        bf[mt] = *(const float4*)&bias[mt * 16 + lq * 4];

    const int r2 = wave * 16 + ln;
    f16x8 b0 = *(const f16x8*)&tile[(size_t)r2 * WT_STRIDE + lq * 8];
    f16x8 b1 = *(const f16x8*)&tile[(size_t)r2 * WT_STRIDE + 32 + lq * 8];
    f32x4 acc2[2][4];
#pragma unroll
    for (int mat = 0; mat < 2; ++mat)
#pragma unroll
        for (int mt = 0; mt < 4; ++mt) {
            f32x4 z = {0.f, 0.f, 0.f, 0.f};
            z = __builtin_amdgcn_mfma_f32_16x16x32_f16(af[mat][mt][0], b0, z, 0, 0, 0);
            z = __builtin_amdgcn_mfma_f32_16x16x32_f16(af[mat][mt][1], b1, z, 0, 0, 0);
            acc2[mat][mt] = z;
        }
    const int node = b * BN + r2;
    if (node < n) {
#pragma unroll
        for (int mt = 0; mt < 4; ++mt) {
            union { __half2 h[2]; float2 f; } u;
            u.h[0] = __floats2half2_rn(acc2[0][mt][0], acc2[0][mt][1]);
            u.h[1] = __floats2half2_rn(acc2[0][mt][2], acc2[0][mt][3]);
            *(float2*)&A2[(size_t)node * 64 + mt * 16 + lq * 4] = u.f;
            union { __half2 h[2]; float2 f; } v;
            v.h[0] = __floats2half2_rn(acc2[1][mt][0] + bf[mt].x, acc2[1][mt][1] + bf[mt].y);
            v.h[1] = __floats2half2_rn(acc2[1][mt][2] + bf[mt].z, acc2[1][mt][3] + bf[mt].w);
            *(float2*)&D2[(size_t)node * 64 + mt * 16 + lq * 4] = v.f;
        }
    }
}

// ---- layer-2 gather from node-sorted P (nstart/ncnt), dynamic rows ----
__global__ __launch_bounds__(256) void gather_csr_combine(const __half* __restrict__ A,
                                                          const __half* __restrict__ Dbuf,
                                                          const int* __restrict__ nstart,
                                                          const int* __restrict__ ncnt,
                                                          const int* __restrict__ P2,
                                                          float* __restrict__ out, int n) {
    __shared__ int wq;
    const int t = threadIdx.x;
    const int b = blockIdx.x;
    if (t == 0) wq = 32;
    __syncthreads();
    const int dg = t & 7;
    const size_t doff = (size_t)dg * 8;
    int r = t >> 3;
    while (r < BN) {
        const int node = b * BN + r;
        if (node < n) {
            const int s0 = nstart[node];
            const int c = ncnt[node];
            float acc[8] = {0.f, 0.f, 0.f, 0.f, 0.f, 0.f, 0.f, 0.f};
            gather_rows(A, P2 + s0, c, doff, acc);
            const float inv = 1.0f / fmaxf((float)c, 1.0f);
            float d8[8] = {0.f, 0.f, 0.f, 0.f, 0.f, 0.f, 0.f, 0.f};
            addh8(d8, *(const float4*)&Dbuf[(size_t)node * 64 + doff]);
            float o[8];
#pragma unroll
            for (int k = 0; k < 8; ++k)
                o[k] = fmaf(acc[k], inv, d8[k]);
            f32x4 v0 = {o[0], o[1], o[2], o[3]};
            f32x4 v1 = {o[4], o[5], o[6], o[7]};
            __builtin_nontemporal_store(v0, (f32x4*)&out[(size_t)node * 64 + doff]);
            __builtin_nontemporal_store(v1, (f32x4*)&out[(size_t)node * 64 + doff + 4]);
        }
        int nr;
        if (dg == 0) nr = atomicAdd(&wq, 1);
        nr = __shfl(nr, (t & 63) & ~7, 64);
        r = nr;
    }
}

extern "C" void kernel_launch(void* const* d_in, const int* in_sizes, int n_in,
                              void* d_out, int out_size, void* d_ws, size_t ws_size,
                              hipStream_t stream) {
    const float* x   = (const float*)d_in[0];
    const int*   ei  = (const int*)d_in[1];
    const float* w1l = (const float*)d_in[2];
    const float* b1l = (const float*)d_in[3];
    const float* w1r = (const float*)d_in[4];
    const float* w2l = (const float*)d_in[5];
    const float* b2l = (const float*)d_in[6];
    const float* w2r = (const float*)d_in[7];
    float* out = (float*)d_out;

    const int N = in_sizes[0] / DIM;   // 100000
    const int E = in_sizes[1] / 2;     // 1600000
    const int* src = ei;
    const int* dst = ei + E;
    const int nbuck = (N + BN - 1) / BN;           // 1563
    const int pb = (E + CHUNK - 1) / CHUNK;        // 391
    const int gb = (N + 255) / 256;                // 391

    // ws: gcur[8*nbuck] | nstart[N] | ncnt[N] | P[nbuck*CAP] |
    //     (align 16) A fp16[N*64] | D fp16[N*64] (=D2) | A2 fp16[N*64]
    int* gcur = (int*)d_ws;
    int* nstart = gcur + 8 * nbuck;
    int* ncnt = nstart + N;
    unsigned* P = (unsigned*)(ncnt + N);
    uintptr_t ap = (uintptr_t)(P + (size_t)nbuck * CAP);
    ap = (ap + 15) & ~(uintptr_t)15;
    __half* A  = (__half*)ap;
    __half* D  = A + (size_t)N * DIM;
    __half* A2 = D + (size_t)N * DIM;

    // ---- build (sharded capacity buckets, single-read) + layer-1 gemm ----
    hipMemsetAsync(gcur, 0, 8 * nbuck * sizeof(int), stream);
    part_gemm_kernel<<<pb + gb, 256, 0, stream>>>(src, dst, gcur, P, E, nbuck, pb,
                                                  x, w1l, w1r, b1l, A, D, N);

    // ---- layer-1 gather + relu + layer-2 gemm (fused); compacts P in place ----
    gather_gemm_kernel<<<nbuck, 256, 0, stream>>>(A, D, gcur, P, nstart, ncnt,
                                                  w2l, w2r, b2l, A2, D, N);

    // ---- layer-2 gather -> fp32 out ----
    gather_csr_combine<<<nbuck, 256, 0, stream>>>(A2, D, nstart, ncnt, (const int*)P, out, N);
}